// Round 1
// baseline (2611.670 us; speedup 1.0000x reference)
//
#include <hip/hip_runtime.h>
#include <hip/hip_bf16.h>

// SAICNet: encoder LSTM (T=20, N=131072, E=32, H=64) + social pool (P=32/scene)
// + decoder LSTM (T=30, S=4096, H=64) + output projection. All fp32.

__device__ __forceinline__ float rcp_(float x) { return __builtin_amdgcn_rcpf(x); }
__device__ __forceinline__ float sigmoid_(float x) { return rcp_(1.0f + __expf(-x)); }
__device__ __forceinline__ float tanh_(float x) {
    float e = __expf(-2.0f * fabsf(x));             // in (0,1], overflow-free
    float t = (1.0f - e) * rcp_(1.0f + e);
    return copysignf(t, x);
}

// ---------------------------------------------------------------------------
// Encoder + social pooling. WG = 512 threads, 128 agents (= 4 scenes of 32).
// Wave g (64 lanes) owns agents [16g, 16g+16); lane j owns gate cols
// {j, 64+j, 128+j, 192+j}. Weights in LDS as [k][j][4] (float4 per (k,j)).
// All per-step LDS dataflow is intra-wave -> no per-step barriers.
// ---------------------------------------------------------------------------
__global__ __launch_bounds__(512, 2) void enc_pool_kernel(
    const float* __restrict__ hist,      // [T,N,2]
    const float* __restrict__ hist_pos,  // [N,2]
    const float* __restrict__ W_ie,      // [2,32]
    const float* __restrict__ b_ie,      // [32]
    const float* __restrict__ Wih,       // [32,256]
    const float* __restrict__ Whh,       // [64,256]
    const float* __restrict__ bih,       // [256]
    const float* __restrict__ bhh,       // [256]
    const float* __restrict__ Wse,       // [2,64]
    const float* __restrict__ bse,       // [64]
    const float* __restrict__ Wmp,       // [128,64]
    const float* __restrict__ bmp,       // [64]
    float* __restrict__ encO,            // [S,128]  (ws)
    int N, int T)
{
    __shared__ __align__(16) float smem[37216];
    float* sWh = smem;              // 16384 floats: [k64][j64][G4]
    float* sWi = smem + 16384;      //  8192 floats: [e32][j64][G4]
    float* sH  = smem + 24576;      //  8192 floats: [a128][k64]
    float* sE  = smem + 32768;      //  4096 floats: [a128][e32]
    float* sIE = smem + 36864;      //    96 floats: W_ie(64) + b_ie(32)
    // pooling-phase aliases (valid after LSTM is done):
    float* sPool = smem;            //  8192: [a128][j64]   (over sWh lo)
    float* sWmp  = smem + 8192;     //  8192: [k128][j64]   (over sWh hi)
    float* sRel  = smem + 16384;    //  8192: [a128][e64]   (over sWi)
    float* sPS   = smem + 36960;    //   256: Wse(128)+bse(64)+bmp(64)

    const int tid = threadIdx.x;
    const int j   = tid & 63;
    const int g   = tid >> 6;
    const int a0  = g << 4;
    const int n0  = blockIdx.x << 7;

    // ---- stage weights (once) ----
    for (int idx = tid; idx < 64 * 256; idx += 512) {
        int k = idx >> 8, col = idx & 255;
        sWh[((k << 6) | (col & 63)) * 4 + (col >> 6)] = Whh[idx];
    }
    for (int idx = tid; idx < 32 * 256; idx += 512) {
        int e = idx >> 8, col = idx & 255;
        sWi[((e << 6) | (col & 63)) * 4 + (col >> 6)] = Wih[idx];
    }
    if (tid < 64)       sIE[tid] = W_ie[tid];
    else if (tid < 96)  sIE[tid] = b_ie[tid - 64];
    for (int idx = tid; idx < 8192; idx += 512) sH[idx] = 0.0f;

    float bg0 = bih[j]       + bhh[j];
    float bg1 = bih[64 + j]  + bhh[64 + j];
    float bg2 = bih[128 + j] + bhh[128 + j];
    float bg3 = bih[192 + j] + bhh[192 + j];

    __syncthreads();

    const float4* Wi4 = reinterpret_cast<const float4*>(sWi);
    const float4* Wh4 = reinterpret_cast<const float4*>(sWh);
    const float4* E4  = reinterpret_cast<const float4*>(sE);
    const float4* H4  = reinterpret_cast<const float4*>(sH);
    const float2* hist2 = reinterpret_cast<const float2*>(hist);

    float c[16];
#pragma unroll
    for (int a = 0; a < 16; ++a) c[a] = 0.0f;

    const int a_emb  = tid >> 2;            // 0..127 (intra-wave: wave g -> its 16 agents)
    const int e_base = (tid & 3) << 3;      // 8 emb dims per thread

    for (int t = 0; t < T; ++t) {
        // embedding: emb = relu(x @ W_ie + b_ie), written by the owning wave
        {
            float2 xy = hist2[(size_t)t * N + (n0 + a_emb)];
#pragma unroll
            for (int q = 0; q < 8; ++q) {
                int e = e_base + q;
                float v = fmaf(xy.x, sIE[e], fmaf(xy.y, sIE[32 + e], sIE[64 + e]));
                sE[(a_emb << 5) + e] = fmaxf(v, 0.0f);
            }
        }
        // gates: acc[G][a] = bias + emb@Wih + h@Whh
        float acc0[16], acc1[16], acc2[16], acc3[16];
#pragma unroll
        for (int a = 0; a < 16; ++a) { acc0[a] = bg0; acc1[a] = bg1; acc2[a] = bg2; acc3[a] = bg3; }

#pragma unroll 2
        for (int eq = 0; eq < 8; ++eq) {
            float4 w0 = Wi4[((eq * 4 + 0) << 6) + j];
            float4 w1 = Wi4[((eq * 4 + 1) << 6) + j];
            float4 w2 = Wi4[((eq * 4 + 2) << 6) + j];
            float4 w3 = Wi4[((eq * 4 + 3) << 6) + j];
#pragma unroll
            for (int a = 0; a < 16; ++a) {
                float4 ev = E4[((a0 + a) << 3) + eq];
                acc0[a] += ev.x * w0.x + ev.y * w1.x + ev.z * w2.x + ev.w * w3.x;
                acc1[a] += ev.x * w0.y + ev.y * w1.y + ev.z * w2.y + ev.w * w3.y;
                acc2[a] += ev.x * w0.z + ev.y * w1.z + ev.z * w2.z + ev.w * w3.z;
                acc3[a] += ev.x * w0.w + ev.y * w1.w + ev.z * w2.w + ev.w * w3.w;
            }
        }
#pragma unroll 2
        for (int kq = 0; kq < 16; ++kq) {
            float4 w0 = Wh4[((kq * 4 + 0) << 6) + j];
            float4 w1 = Wh4[((kq * 4 + 1) << 6) + j];
            float4 w2 = Wh4[((kq * 4 + 2) << 6) + j];
            float4 w3 = Wh4[((kq * 4 + 3) << 6) + j];
#pragma unroll
            for (int a = 0; a < 16; ++a) {
                float4 hv = H4[((a0 + a) << 4) + kq];
                acc0[a] += hv.x * w0.x + hv.y * w1.x + hv.z * w2.x + hv.w * w3.x;
                acc1[a] += hv.x * w0.y + hv.y * w1.y + hv.z * w2.y + hv.w * w3.y;
                acc2[a] += hv.x * w0.z + hv.y * w1.z + hv.z * w2.z + hv.w * w3.z;
                acc3[a] += hv.x * w0.w + hv.y * w1.w + hv.z * w2.w + hv.w * w3.w;
            }
        }
        // LSTM cell update; h written back to LDS (own rows only)
#pragma unroll
        for (int a = 0; a < 16; ++a) {
            float i_ = sigmoid_(acc0[a]);
            float f_ = sigmoid_(acc1[a]);
            float gg = tanh_(acc2[a]);
            float o_ = sigmoid_(acc3[a]);
            c[a] = fmaf(f_, c[a], i_ * gg);
            sH[((a0 + a) << 6) + j] = o_ * tanh_(c[a]);
        }
    }

    __syncthreads();   // all waves done with sWh/sWi before aliasing

    // ---- social pooling ----
    for (int idx = tid; idx < 8192; idx += 512) sWmp[idx] = Wmp[idx];
    if (tid < 128)      sPS[tid] = Wse[tid];
    else if (tid < 192) sPS[tid] = bse[tid - 128];
    else if (tid < 256) sPS[tid] = bmp[tid - 192];
    __syncthreads();   // staged weights visible

    // rel_emb = relu((pos_j - pos_0) @ Wse + bse), intra-wave rows
    {
        const float2* pos2 = reinterpret_cast<const float2*>(hist_pos);
        int nA = n0 + a_emb;
        int nB = n0 + ((a_emb >> 5) << 5);       // first agent of the scene
        float2 pa = pos2[nA], pb = pos2[nB];
        float px = pa.x - pb.x, py = pa.y - pb.y;
        int eb = (tid & 3) << 4;
#pragma unroll
        for (int q = 0; q < 16; ++q) {
            int e = eb + q;
            float v = fmaf(px, sPS[e], fmaf(py, sPS[64 + e], sPS[128 + e]));
            sRel[(a_emb << 6) + e] = fmaxf(v, 0.0f);
        }
    }
    // pooled = relu([H | rel] @ Wmp + bmp)
    {
        float pool[16];
        float bm = sPS[192 + j];
#pragma unroll
        for (int a = 0; a < 16; ++a) pool[a] = bm;
        for (int k = 0; k < 64; ++k) {
            float wm = sWmp[(k << 6) + j];
#pragma unroll
            for (int a = 0; a < 16; ++a)
                pool[a] = fmaf(sH[((a0 + a) << 6) + k], wm, pool[a]);
        }
        for (int k = 0; k < 64; ++k) {
            float wm = sWmp[((64 + k) << 6) + j];
#pragma unroll
            for (int a = 0; a < 16; ++a)
                pool[a] = fmaf(sRel[((a0 + a) << 6) + k], wm, pool[a]);
        }
#pragma unroll
        for (int a = 0; a < 16; ++a)
            sPool[((a0 + a) << 6) + j] = fmaxf(pool[a], 0.0f);
    }
    __syncthreads();   // cross-wave max next

    if (tid < 256) {
        int sl = tid >> 6;                       // local scene 0..3
        float m = -3.4e38f;
        for (int a = 0; a < 32; ++a)
            m = fmaxf(m, sPool[((sl * 32 + a) << 6) + j]);
        int sg = (blockIdx.x << 2) + sl;
        encO[sg * 128 + j]      = m;                          // soc
        encO[sg * 128 + 64 + j] = sH[((sl << 5) << 6) + j];   // tgt = h of agent 0
    }
}

// ---------------------------------------------------------------------------
// Decoder: WG = 256 threads = 4 waves = 4 scenes. Lane j owns h[j], c[j] and
// gate cols {j, 64+j, 128+j, 192+j}. Constant input gx hoisted to registers.
// Output projection via wave shfl_xor reduction.
// ---------------------------------------------------------------------------
__global__ __launch_bounds__(256, 2) void dec_kernel(
    const float* __restrict__ enc,    // [S,128] (ws)
    const float* __restrict__ Wih_d,  // [128,256]
    const float* __restrict__ Whh_d,  // [64,256]
    const float* __restrict__ bih_d,  // [256]
    const float* __restrict__ bhh_d,  // [256]
    const float* __restrict__ Wop,    // [64,2]
    const float* __restrict__ bop,    // [2]
    float* __restrict__ out,          // [TOUT,S,2]
    int S, int TOUT)
{
    __shared__ __align__(16) float sWh[16384];   // [k64][j64][G4]
    __shared__ __align__(16) float sHd[256];     // [w4][j64]

    const int tid = threadIdx.x;
    const int j = tid & 63;
    const int w = tid >> 6;
    const int s = (blockIdx.x << 2) + w;

    for (int idx = tid; idx < 64 * 256; idx += 256) {
        int k = idx >> 8, col = idx & 255;
        sWh[((k << 6) | (col & 63)) * 4 + (col >> 6)] = Whh_d[idx];
    }
    sHd[tid] = 0.0f;

    // gx = enc @ Wih_d + bih_d + bhh_d (constant across steps)
    float gx0 = bih_d[j]       + bhh_d[j];
    float gx1 = bih_d[64 + j]  + bhh_d[64 + j];
    float gx2 = bih_d[128 + j] + bhh_d[128 + j];
    float gx3 = bih_d[192 + j] + bhh_d[192 + j];
    for (int k = 0; k < 128; ++k) {
        float ev = enc[s * 128 + k];
        const float* col = Wih_d + k * 256;
        gx0 = fmaf(ev, col[j], gx0);
        gx1 = fmaf(ev, col[64 + j], gx1);
        gx2 = fmaf(ev, col[128 + j], gx2);
        gx3 = fmaf(ev, col[192 + j], gx3);
    }
    float wop0 = Wop[j * 2], wop1 = Wop[j * 2 + 1];
    float bop0 = bop[0], bop1 = bop[1];

    __syncthreads();

    const float4* Wh4 = reinterpret_cast<const float4*>(sWh);
    const float4* H4  = reinterpret_cast<const float4*>(sHd);

    float c = 0.0f;
    for (int t = 0; t < TOUT; ++t) {
        float g0 = gx0, g1 = gx1, g2 = gx2, g3 = gx3;
#pragma unroll 4
        for (int kq = 0; kq < 16; ++kq) {
            float4 hv = H4[(w << 4) + kq];
            float4 w0 = Wh4[((kq * 4 + 0) << 6) + j];
            float4 w1 = Wh4[((kq * 4 + 1) << 6) + j];
            float4 w2 = Wh4[((kq * 4 + 2) << 6) + j];
            float4 w3 = Wh4[((kq * 4 + 3) << 6) + j];
            g0 += hv.x * w0.x + hv.y * w1.x + hv.z * w2.x + hv.w * w3.x;
            g1 += hv.x * w0.y + hv.y * w1.y + hv.z * w2.y + hv.w * w3.y;
            g2 += hv.x * w0.z + hv.y * w1.z + hv.z * w2.z + hv.w * w3.z;
            g3 += hv.x * w0.w + hv.y * w1.w + hv.z * w2.w + hv.w * w3.w;
        }
        float i_ = sigmoid_(g0);
        float f_ = sigmoid_(g1);
        float gg = tanh_(g2);
        float o_ = sigmoid_(g3);
        c = fmaf(f_, c, i_ * gg);
        float h = o_ * tanh_(c);

        float r0 = h * wop0, r1 = h * wop1;
#pragma unroll
        for (int off = 32; off > 0; off >>= 1) {
            r0 += __shfl_xor(r0, off);
            r1 += __shfl_xor(r1, off);
        }
        if (j == 0) {
            float* op = out + ((size_t)t * S + s) * 2;
            op[0] = r0 + bop0;
            op[1] = r1 + bop1;
        }
        sHd[(w << 6) + j] = h;   // own row; intra-wave ordering suffices
    }
}

extern "C" void kernel_launch(void* const* d_in, const int* in_sizes, int n_in,
                              void* d_out, int out_size, void* d_ws, size_t ws_size,
                              hipStream_t stream) {
    (void)n_in; (void)ws_size;
    const float* hist     = (const float*)d_in[0];
    const float* hist_pos = (const float*)d_in[1];
    const float* W_ie     = (const float*)d_in[2];
    const float* b_ie     = (const float*)d_in[3];
    const float* Wih_e    = (const float*)d_in[4];
    const float* Whh_e    = (const float*)d_in[5];
    const float* bih_e    = (const float*)d_in[6];
    const float* bhh_e    = (const float*)d_in[7];
    const float* Wse      = (const float*)d_in[8];
    const float* bse      = (const float*)d_in[9];
    const float* Wmp      = (const float*)d_in[10];
    const float* bmp      = (const float*)d_in[11];
    const float* Wih_d    = (const float*)d_in[12];
    const float* Whh_d    = (const float*)d_in[13];
    const float* bih_d    = (const float*)d_in[14];
    const float* bhh_d    = (const float*)d_in[15];
    const float* Wop      = (const float*)d_in[16];
    const float* bop      = (const float*)d_in[17];

    const int N = in_sizes[1] / 2;
    const int T = in_sizes[0] / (N * 2);
    const int S = in_sizes[18] - 1;
    const int TOUT = out_size / (S * 2);

    float* enc = (float*)d_ws;   // [S,128] = 2 MB

    enc_pool_kernel<<<dim3(N / 128), dim3(512), 0, stream>>>(
        hist, hist_pos, W_ie, b_ie, Wih_e, Whh_e, bih_e, bhh_e,
        Wse, bse, Wmp, bmp, enc, N, T);

    dec_kernel<<<dim3(S / 4), dim3(256), 0, stream>>>(
        enc, Wih_d, Whh_d, bih_d, bhh_d, Wop, bop, (float*)d_out, S, TOUT);
}

// Round 2
// 574.250 us; speedup vs baseline: 4.5480x; 4.5480x over previous
//
#include <hip/hip_runtime.h>
#include <hip/hip_bf16.h>

// SAICNet: encoder LSTM (T=20, N=131072, E=32, H=64) via bf16 split-precision
// MFMA + social pool (P=32/scene) fused; decoder LSTM (T=30, S=4096) fp32 VALU.

typedef short short8 __attribute__((ext_vector_type(8)));
typedef float f32x4  __attribute__((ext_vector_type(4)));

__device__ __forceinline__ float rcp_(float x) { return __builtin_amdgcn_rcpf(x); }
__device__ __forceinline__ float sigmoid_(float x) { return rcp_(1.0f + __expf(-x)); }
__device__ __forceinline__ float tanh_(float x) {
    float e = __expf(-2.0f * fabsf(x));             // in (0,1], overflow-free
    float t = (1.0f - e) * rcp_(1.0f + e);
    return copysignf(t, x);
}
// split fp32 into bf16 hi (truncate) + bf16 lo (truncate of remainder):
// hi+lo reconstructs f to ~2^-16 relative.
__device__ __forceinline__ void split_(float f, short& h, short& l) {
    unsigned u = __builtin_bit_cast(unsigned, f);
    h = (short)(u >> 16);
    float r = f - __builtin_bit_cast(float, u & 0xFFFF0000u);
    l = (short)(__builtin_bit_cast(unsigned, r) >> 16);
}
__device__ __forceinline__ float b2f_(short s) {
    return __builtin_bit_cast(float, ((unsigned)(unsigned short)s) << 16);
}

#define XSTR 200   // shorts per agent row: [emb_hi 32 | h_hi 64 | emb_lo 32 | h_lo 64 | pad 8]

// ---------------------------------------------------------------------------
// Encoder + pooling. 512 threads = 8 waves; block = 128 agents (4 scenes).
// Wave w = (mh = w>>2, p = w&3): owns agents [64mh,64mh+64) (4 M-tiles) and
// gate cols {64g + 16p + 0..15 : g=0..3} (4 N-tiles, one j-tile, all gates).
// B (weights, split hi/lo) held in VGPRs; X (emb/h, split hi/lo) in LDS.
// MFMA 16x16x32 bf16: A lane: row=l&15, k=(l>>4)*8+i; B lane: col=l&15, same k;
// D: col=l&15, row=(l>>4)*4+reg  [m89-verified].
// ---------------------------------------------------------------------------
__global__ __launch_bounds__(512, 2) void enc_pool_kernel(
    const float* __restrict__ hist,      // [T,N,2]
    const float* __restrict__ hist_pos,  // [N,2]
    const float* __restrict__ W_ie,      // [2,32]
    const float* __restrict__ b_ie,      // [32]
    const float* __restrict__ Wih,       // [32,256]
    const float* __restrict__ Whh,       // [64,256]
    const float* __restrict__ bih,       // [256]
    const float* __restrict__ bhh,       // [256]
    const float* __restrict__ Wse,       // [2,64]
    const float* __restrict__ bse,       // [64]
    const float* __restrict__ Wmp,       // [128,64]
    const float* __restrict__ bmp,       // [64]
    float* __restrict__ encO,            // [S,128]  (ws)
    int N, int T)
{
    __shared__ __align__(16) float smem[38240];
    float* sXf   = smem;             // 12800 f (= 25600 shorts): X buffer
    short* sXs   = (short*)smem;
    float* sIE   = smem + 12800;     //    96: W_ie(64)+b_ie(32)
    float* sPS   = smem + 12896;     //   256: Wse(128)+bse(64)+bmp(64)
    float* sHf   = smem + 13152;     // 128*68: h_enc fp32 (padded stride 68)
    float* sWmp  = smem + 21856;     //  8192: Wmp
    float* sRelf = smem + 30048;     //  8192: rel_emb
    float* sPool = smem;             //  8192: pooled (aliases sX, used after)

    const int tid  = threadIdx.x;
    const int lane = tid & 63;
    const int w    = tid >> 6;
    const int mh   = w >> 2;
    const int p    = w & 3;
    const int l15  = lane & 15;
    const int l4   = lane >> 4;
    const int n0   = blockIdx.x << 7;

    // ---- B fragments (weights) into registers, split hi/lo ----
    short8 Bhi[3][4], Blo[3][4];     // [ktile][ntile(gate)]
#pragma unroll
    for (int n = 0; n < 4; ++n) {
        int c = (n << 6) + (p << 4) + l15;
#pragma unroll
        for (int kt = 0; kt < 3; ++kt) {
            short8 bh, bl;
#pragma unroll
            for (int i = 0; i < 8; ++i) {
                int k = kt * 32 + l4 * 8 + i;
                float wv = (k < 32) ? Wih[k * 256 + c] : Whh[(k - 32) * 256 + c];
                short hh, ll; split_(wv, hh, ll);
                bh[i] = hh; bl[i] = ll;
            }
            Bhi[kt][n] = bh; Blo[kt][n] = bl;
        }
    }
    float bias[4];
#pragma unroll
    for (int n = 0; n < 4; ++n) {
        int c = (n << 6) + (p << 4) + l15;
        bias[n] = bih[c] + bhh[c];
    }

    // ---- zero X, stage small tables ----
    for (int i = tid; i < 12800; i += 512) ((int*)sXf)[i] = 0;
    if (tid < 64)      sIE[tid] = W_ie[tid];
    else if (tid < 96) sIE[tid] = b_ie[tid - 64];
    __syncthreads();

    const float2* hist2 = (const float2*)hist;
    const int ag = tid >> 2;          // agent this thread embeds (0..127)
    const int eb = (tid & 3) << 3;    // its 8 emb dims

    auto emb_write = [&](int t) {
        float2 xy = hist2[(size_t)t * N + n0 + ag];
        short8 hv, lv;
#pragma unroll
        for (int q = 0; q < 8; ++q) {
            int e = eb + q;
            float v = fmaf(xy.x, sIE[e], fmaf(xy.y, sIE[32 + e], sIE[64 + e]));
            v = fmaxf(v, 0.0f);
            short hh, ll; split_(v, hh, ll);
            hv[q] = hh; lv[q] = ll;
        }
        *(short8*)(sXs + ag * XSTR + eb) = hv;
        *(short8*)(sXs + ag * XSTR + 96 + eb) = lv;
    };
    emb_write(0);
    __syncthreads();

    float cst[4][4];
#pragma unroll
    for (int m = 0; m < 4; ++m)
#pragma unroll
        for (int r = 0; r < 4; ++r) cst[m][r] = 0.0f;

    const int jcol = (p << 4) + l15;

    for (int t = 0; t < T; ++t) {
        // ---- Phase 1: gates = bias + [emb|h] @ W  (3 K-tiles of 32) ----
        f32x4 acc[4][4];
#pragma unroll
        for (int m = 0; m < 4; ++m)
#pragma unroll
            for (int n = 0; n < 4; ++n)
                acc[m][n] = (f32x4){bias[n], bias[n], bias[n], bias[n]};

#pragma unroll
        for (int kt = 0; kt < 3; ++kt) {
#pragma unroll
            for (int m = 0; m < 4; ++m) {
                const short* base = sXs + ((mh << 6) + (m << 4) + l15) * XSTR + kt * 32 + l4 * 8;
                short8 ahi = *(const short8*)(base);
                short8 alo = *(const short8*)(base + 96);
#pragma unroll
                for (int n = 0; n < 4; ++n) {
                    acc[m][n] = __builtin_amdgcn_mfma_f32_16x16x32_bf16(ahi, Bhi[kt][n], acc[m][n], 0, 0, 0);
                    acc[m][n] = __builtin_amdgcn_mfma_f32_16x16x32_bf16(alo, Bhi[kt][n], acc[m][n], 0, 0, 0);
                    acc[m][n] = __builtin_amdgcn_mfma_f32_16x16x32_bf16(ahi, Blo[kt][n], acc[m][n], 0, 0, 0);
                }
            }
        }
        __syncthreads();   // all reads of X done before rewrites

        // ---- Phase 2: cell update + h write-back (+ next emb) ----
#pragma unroll
        for (int m = 0; m < 4; ++m) {
            int a = (mh << 6) + (m << 4) + (l4 << 2);
#pragma unroll
            for (int r = 0; r < 4; ++r) {
                float i_ = sigmoid_(acc[m][0][r]);
                float f_ = sigmoid_(acc[m][1][r]);
                float g_ = tanh_(acc[m][2][r]);
                float o_ = sigmoid_(acc[m][3][r]);
                cst[m][r] = fmaf(f_, cst[m][r], i_ * g_);
                float h = o_ * tanh_(cst[m][r]);
                short hh, ll; split_(h, hh, ll);
                sXs[(a + r) * XSTR + 32 + jcol]  = hh;
                sXs[(a + r) * XSTR + 128 + jcol] = ll;
            }
        }
        if (t + 1 < T) emb_write(t + 1);
        __syncthreads();   // writes visible before next step's reads
    }

    // ---- social pooling ----
    {   // h_enc (hi+lo) -> fp32 sHf; stage Wmp, small tables
        int kb = (tid & 3) << 4;
        const short* hb = sXs + ag * XSTR + 32 + kb;
        short8 h0 = *(const short8*)(hb);
        short8 h1 = *(const short8*)(hb + 8);
        short8 l0 = *(const short8*)(hb + 96);
        short8 l1 = *(const short8*)(hb + 104);
#pragma unroll
        for (int q = 0; q < 8; ++q) {
            sHf[ag * 68 + kb + q]     = b2f_(h0[q]) + b2f_(l0[q]);
            sHf[ag * 68 + kb + 8 + q] = b2f_(h1[q]) + b2f_(l1[q]);
        }
    }
    for (int i = tid; i < 8192; i += 512) sWmp[i] = Wmp[i];
    if (tid < 128)      sPS[tid] = Wse[tid];
    else if (tid < 192) sPS[tid] = bse[tid - 128];
    else if (tid < 256) sPS[tid] = bmp[tid - 192];
    __syncthreads();

    {   // rel_emb = relu((pos - pos_scene0) @ Wse + bse): own-wave rows
        const float2* pos2 = (const float2*)hist_pos;
        float2 pa = pos2[n0 + ag];
        float2 pb = pos2[n0 + ((ag >> 5) << 5)];
        float px = pa.x - pb.x, py = pa.y - pb.y;
        int ebq = (tid & 3) << 4;
#pragma unroll
        for (int q = 0; q < 16; ++q) {
            int e = ebq + q;
            float v = fmaf(px, sPS[e], fmaf(py, sPS[64 + e], sPS[128 + e]));
            sRelf[(ag << 6) + e] = fmaxf(v, 0.0f);
        }
    }
    {   // pooled = relu([H|rel] @ Wmp + bmp): wave w -> agents [16w,16w+16)
        float pool[16];
        float bm = sPS[192 + lane];
#pragma unroll
        for (int a = 0; a < 16; ++a) pool[a] = bm;
        int a0 = w << 4;
        for (int k = 0; k < 64; ++k) {
            float wm = sWmp[(k << 6) + lane];
#pragma unroll
            for (int a = 0; a < 16; ++a)
                pool[a] = fmaf(sHf[(a0 + a) * 68 + k], wm, pool[a]);
        }
        for (int k = 0; k < 64; ++k) {
            float wm = sWmp[((64 + k) << 6) + lane];
#pragma unroll
            for (int a = 0; a < 16; ++a)
                pool[a] = fmaf(sRelf[((a0 + a) << 6) + k], wm, pool[a]);
        }
#pragma unroll
        for (int a = 0; a < 16; ++a)
            sPool[((a0 + a) << 6) + lane] = fmaxf(pool[a], 0.0f);
    }
    __syncthreads();

    if (tid < 256) {
        int sl = tid >> 6, j = tid & 63;
        float mx = -3.4e38f;
        for (int a = 0; a < 32; ++a)
            mx = fmaxf(mx, sPool[((sl * 32 + a) << 6) + j]);
        int sg = (blockIdx.x << 2) + sl;
        encO[sg * 128 + j]      = mx;                    // soc
        encO[sg * 128 + 64 + j] = sHf[(sl * 32) * 68 + j]; // tgt = h of agent 0
    }
}

// ---------------------------------------------------------------------------
// Decoder: unchanged from round 0 (correct; profile next round).
// ---------------------------------------------------------------------------
__global__ __launch_bounds__(256, 2) void dec_kernel(
    const float* __restrict__ enc,    // [S,128] (ws)
    const float* __restrict__ Wih_d,  // [128,256]
    const float* __restrict__ Whh_d,  // [64,256]
    const float* __restrict__ bih_d,  // [256]
    const float* __restrict__ bhh_d,  // [256]
    const float* __restrict__ Wop,    // [64,2]
    const float* __restrict__ bop,    // [2]
    float* __restrict__ out,          // [TOUT,S,2]
    int S, int TOUT)
{
    __shared__ __align__(16) float sWh[16384];   // [k64][j64][G4]
    __shared__ __align__(16) float sHd[256];     // [w4][j64]

    const int tid = threadIdx.x;
    const int j = tid & 63;
    const int w = tid >> 6;
    const int s = (blockIdx.x << 2) + w;

    for (int idx = tid; idx < 64 * 256; idx += 256) {
        int k = idx >> 8, col = idx & 255;
        sWh[((k << 6) | (col & 63)) * 4 + (col >> 6)] = Whh_d[idx];
    }
    sHd[tid] = 0.0f;

    float gx0 = bih_d[j]       + bhh_d[j];
    float gx1 = bih_d[64 + j]  + bhh_d[64 + j];
    float gx2 = bih_d[128 + j] + bhh_d[128 + j];
    float gx3 = bih_d[192 + j] + bhh_d[192 + j];
    for (int k = 0; k < 128; ++k) {
        float ev = enc[s * 128 + k];
        const float* col = Wih_d + k * 256;
        gx0 = fmaf(ev, col[j], gx0);
        gx1 = fmaf(ev, col[64 + j], gx1);
        gx2 = fmaf(ev, col[128 + j], gx2);
        gx3 = fmaf(ev, col[192 + j], gx3);
    }
    float wop0 = Wop[j * 2], wop1 = Wop[j * 2 + 1];
    float bop0 = bop[0], bop1 = bop[1];

    __syncthreads();

    const float4* Wh4 = reinterpret_cast<const float4*>(sWh);
    const float4* H4  = reinterpret_cast<const float4*>(sHd);

    float c = 0.0f;
    for (int t = 0; t < TOUT; ++t) {
        float g0 = gx0, g1 = gx1, g2 = gx2, g3 = gx3;
#pragma unroll 4
        for (int kq = 0; kq < 16; ++kq) {
            float4 hv = H4[(w << 4) + kq];
            float4 w0 = Wh4[((kq * 4 + 0) << 6) + j];
            float4 w1 = Wh4[((kq * 4 + 1) << 6) + j];
            float4 w2 = Wh4[((kq * 4 + 2) << 6) + j];
            float4 w3 = Wh4[((kq * 4 + 3) << 6) + j];
            g0 += hv.x * w0.x + hv.y * w1.x + hv.z * w2.x + hv.w * w3.x;
            g1 += hv.x * w0.y + hv.y * w1.y + hv.z * w2.y + hv.w * w3.y;
            g2 += hv.x * w0.z + hv.y * w1.z + hv.z * w2.z + hv.w * w3.z;
            g3 += hv.x * w0.w + hv.y * w1.w + hv.z * w2.w + hv.w * w3.w;
        }
        float i_ = sigmoid_(g0);
        float f_ = sigmoid_(g1);
        float gg = tanh_(g2);
        float o_ = sigmoid_(g3);
        c = fmaf(f_, c, i_ * gg);
        float h = o_ * tanh_(c);

        float r0 = h * wop0, r1 = h * wop1;
#pragma unroll
        for (int off = 32; off > 0; off >>= 1) {
            r0 += __shfl_xor(r0, off);
            r1 += __shfl_xor(r1, off);
        }
        if (j == 0) {
            float* op = out + ((size_t)t * S + s) * 2;
            op[0] = r0 + bop0;
            op[1] = r1 + bop1;
        }
        sHd[(w << 6) + j] = h;
    }
}

extern "C" void kernel_launch(void* const* d_in, const int* in_sizes, int n_in,
                              void* d_out, int out_size, void* d_ws, size_t ws_size,
                              hipStream_t stream) {
    (void)n_in; (void)ws_size;
    const float* hist     = (const float*)d_in[0];
    const float* hist_pos = (const float*)d_in[1];
    const float* W_ie     = (const float*)d_in[2];
    const float* b_ie     = (const float*)d_in[3];
    const float* Wih_e    = (const float*)d_in[4];
    const float* Whh_e    = (const float*)d_in[5];
    const float* bih_e    = (const float*)d_in[6];
    const float* bhh_e    = (const float*)d_in[7];
    const float* Wse      = (const float*)d_in[8];
    const float* bse      = (const float*)d_in[9];
    const float* Wmp      = (const float*)d_in[10];
    const float* bmp      = (const float*)d_in[11];
    const float* Wih_d    = (const float*)d_in[12];
    const float* Whh_d    = (const float*)d_in[13];
    const float* bih_d    = (const float*)d_in[14];
    const float* bhh_d    = (const float*)d_in[15];
    const float* Wop      = (const float*)d_in[16];
    const float* bop      = (const float*)d_in[17];

    const int N = in_sizes[1] / 2;
    const int T = in_sizes[0] / (N * 2);
    const int S = in_sizes[18] - 1;
    const int TOUT = out_size / (S * 2);

    float* enc = (float*)d_ws;   // [S,128] = 2 MB

    enc_pool_kernel<<<dim3(N / 128), dim3(512), 0, stream>>>(
        hist, hist_pos, W_ie, b_ie, Wih_e, Whh_e, bih_e, bhh_e,
        Wse, bse, Wmp, bmp, enc, N, T);

    dec_kernel<<<dim3(S / 4), dim3(256), 0, stream>>>(
        enc, Wih_d, Whh_d, bih_d, bhh_d, Wop, bop, (float*)d_out, S, TOUT);
}

// Round 3
// 487.973 us; speedup vs baseline: 5.3521x; 1.1768x over previous
//
#include <hip/hip_runtime.h>
#include <hip/hip_bf16.h>

// SAICNet: encoder LSTM (T=20, N=131072, E=32, H=64) via 2-term split-bf16
// MFMA, double-buffered X (1 barrier/step), fused register pooling;
// decoder LSTM (T=30, S=4096, H=64) fp32 VALU.

typedef short short8 __attribute__((ext_vector_type(8)));
typedef float f32x4  __attribute__((ext_vector_type(4)));

__device__ __forceinline__ float rcp_(float x) { return __builtin_amdgcn_rcpf(x); }
__device__ __forceinline__ float sigmoid_(float x) { return rcp_(1.0f + __expf(-x)); }
__device__ __forceinline__ float tanh_(float x) {
    float e = __expf(-2.0f * fabsf(x));
    float t = (1.0f - e) * rcp_(1.0f + e);
    return copysignf(t, x);
}
__device__ __forceinline__ short bf16rne_(float v) {
    unsigned u = __builtin_bit_cast(unsigned, v);
    u += 0x7FFF + ((u >> 16) & 1);
    return (short)(u >> 16);
}
__device__ __forceinline__ short bf16tr_(float v) {
    return (short)(__builtin_bit_cast(unsigned, v) >> 16);
}
__device__ __forceinline__ float b2f_(short s) {
    return __builtin_bit_cast(float, ((unsigned)(unsigned short)s) << 16);
}
__device__ __forceinline__ void split_(float w, short& h, short& l) {
    h = bf16tr_(w);
    l = bf16rne_(w - b2f_(h));
}

#define XSTR 168   // shorts/row: [emb 0..31 | h_hi 32..95 | h_lo 96..159 | pad]
// 84 dwords stride == 20 mod 32 -> 2-way LDS bank aliasing (free)

// ---------------------------------------------------------------------------
// Encoder + pooling. 256 threads = 4 waves; block = 64 agents (2 scenes).
// Wave p owns gate cols {64g + 16p + l15 : g=0..3} for ALL 64 agents (4 M-tiles).
// W (split hi/lo) in VGPRs; X double-buffered in LDS (read t&1, write (t+1)&1)
// -> ONE barrier per step. Gate terms kept: e*Whi + e*Wlo + hhi*Whi + hlo*Whi
// + hhi*Wlo (drop hlo*Wlo ~ 2^-18).
// MFMA 16x16x32 bf16: A row=l&15, k=(l>>4)*8+i; D col=l&15, row=(l>>4)*4+reg.
// ---------------------------------------------------------------------------
__global__ __launch_bounds__(256, 3) void enc_pool_kernel(
    const float* __restrict__ hist,      // [T,N,2]
    const float* __restrict__ hist_pos,  // [N,2]
    const float* __restrict__ W_ie,      // [2,32]
    const float* __restrict__ b_ie,      // [32]
    const float* __restrict__ Wih,       // [32,256]
    const float* __restrict__ Whh,       // [64,256]
    const float* __restrict__ bih,       // [256]
    const float* __restrict__ bhh,       // [256]
    const float* __restrict__ Wse,       // [2,64]
    const float* __restrict__ bse,       // [64]
    const float* __restrict__ Wmp,       // [128,64]
    const float* __restrict__ bmp,       // [64]
    float* __restrict__ encO,            // [S,128] (ws)
    int N, int T)
{
    __shared__ __align__(16) short sX[2][64 * XSTR];  // 43008 B
    __shared__ float sIE[96];    // W_ie(64)+b_ie(32)
    __shared__ float sWse[192];  // Wse(128)+bse(64)
    __shared__ float sTgt[128];  // exact h of scene-first agents [2][64]

    const int tid = threadIdx.x;
    const int l15 = tid & 15;
    const int l4  = (tid & 63) >> 4;
    const int p   = tid >> 6;           // wave id = col-tile owner
    const int n0  = blockIdx.x << 6;    // first agent of block
    const int jcol = (p << 4) + l15;    // h column this lane owns

    // ---- W fragments (split) into registers ----
    short8 BihH[4], BihL[4];        // emb k-tile, per gate n
    short8 BhhH[2][4], BhhL[2][4];  // h k-tiles,  per gate n
    float bias[4];
#pragma unroll
    for (int n = 0; n < 4; ++n) {
        int c = (n << 6) + jcol;
        short8 bh, bl;
#pragma unroll
        for (int i = 0; i < 8; ++i) {
            short hh, ll; split_(Wih[(l4 * 8 + i) * 256 + c], hh, ll);
            bh[i] = hh; bl[i] = ll;
        }
        BihH[n] = bh; BihL[n] = bl;
#pragma unroll
        for (int kt = 0; kt < 2; ++kt) {
            short8 ch, cl;
#pragma unroll
            for (int i = 0; i < 8; ++i) {
                short hh, ll; split_(Whh[(kt * 32 + l4 * 8 + i) * 256 + c], hh, ll);
                ch[i] = hh; cl[i] = ll;
            }
            BhhH[kt][n] = ch; BhhL[kt][n] = cl;
        }
        bias[n] = bih[c] + bhh[c];
    }

    // ---- zero buf0, stage small tables ----
    for (int i = tid; i < 64 * XSTR / 2; i += 256) ((int*)sX[0])[i] = 0;
    if (tid < 64)       sIE[tid] = W_ie[tid];
    else if (tid < 96)  sIE[tid] = b_ie[tid - 64];
    if (tid < 128)      sWse[tid] = Wse[tid];
    else if (tid < 192) sWse[tid] = bse[tid - 128];
    __syncthreads();

    const float2* hist2 = (const float2*)hist;
    const int ag = tid >> 2;          // agent this thread embeds (0..63)
    const int eb = (tid & 3) << 3;    // its 8 emb dims

    auto emb_write = [&](int t) {
        float2 xy = hist2[(size_t)t * N + n0 + ag];
        short8 ev;
#pragma unroll
        for (int q = 0; q < 8; ++q) {
            int e = eb + q;
            float v = fmaf(xy.x, sIE[e], fmaf(xy.y, sIE[32 + e], sIE[64 + e]));
            ev[q] = bf16rne_(fmaxf(v, 0.0f));
        }
        *(short8*)(sX[t & 1] + ag * XSTR + eb) = ev;
    };
    emb_write(0);
    __syncthreads();

    float cst[4][4];
#pragma unroll
    for (int m = 0; m < 4; ++m)
#pragma unroll
        for (int r = 0; r < 4; ++r) cst[m][r] = 0.0f;

    for (int t = 0; t < T; ++t) {
        const short* bR = sX[t & 1];
        short* bW = sX[(t + 1) & 1];
#pragma unroll
        for (int m = 0; m < 4; ++m) {
            const short* row = bR + ((m << 4) + l15) * XSTR + l4 * 8;
            short8 aE  = *(const short8*)(row);
            short8 aH0 = *(const short8*)(row + 32);
            short8 aH1 = *(const short8*)(row + 64);
            short8 aL0 = *(const short8*)(row + 96);
            short8 aL1 = *(const short8*)(row + 128);
            f32x4 acc[4];
#pragma unroll
            for (int n = 0; n < 4; ++n)
                acc[n] = (f32x4){bias[n], bias[n], bias[n], bias[n]};
#pragma unroll
            for (int n = 0; n < 4; ++n) {
                acc[n] = __builtin_amdgcn_mfma_f32_16x16x32_bf16(aE,  BihH[n],    acc[n], 0, 0, 0);
                acc[n] = __builtin_amdgcn_mfma_f32_16x16x32_bf16(aE,  BihL[n],    acc[n], 0, 0, 0);
                acc[n] = __builtin_amdgcn_mfma_f32_16x16x32_bf16(aH0, BhhH[0][n], acc[n], 0, 0, 0);
                acc[n] = __builtin_amdgcn_mfma_f32_16x16x32_bf16(aL0, BhhH[0][n], acc[n], 0, 0, 0);
                acc[n] = __builtin_amdgcn_mfma_f32_16x16x32_bf16(aH0, BhhL[0][n], acc[n], 0, 0, 0);
                acc[n] = __builtin_amdgcn_mfma_f32_16x16x32_bf16(aH1, BhhH[1][n], acc[n], 0, 0, 0);
                acc[n] = __builtin_amdgcn_mfma_f32_16x16x32_bf16(aL1, BhhH[1][n], acc[n], 0, 0, 0);
                acc[n] = __builtin_amdgcn_mfma_f32_16x16x32_bf16(aH1, BhhL[1][n], acc[n], 0, 0, 0);
            }
#pragma unroll
            for (int r = 0; r < 4; ++r) {
                float i_ = sigmoid_(acc[0][r]);
                float f_ = sigmoid_(acc[1][r]);
                float g_ = tanh_(acc[2][r]);
                float o_ = sigmoid_(acc[3][r]);
                cst[m][r] = fmaf(f_, cst[m][r], i_ * g_);
                float h = o_ * tanh_(cst[m][r]);
                short hh = bf16tr_(h);
                short hl = bf16rne_(h - b2f_(hh));
                int rw = (m << 4) + (l4 << 2) + r;
                bW[rw * XSTR + 32 + jcol] = hh;
                bW[rw * XSTR + 96 + jcol] = hl;
                if (t == T - 1 && l4 == 0 && (m & 1) == 0 && r == 0)
                    sTgt[(m >> 1) * 64 + jcol] = h;   // exact h of scene-first agent
            }
        }
        if (t + 1 < T) emb_write(t + 1);
        __syncthreads();
    }

    // ---- social pooling: rel into dead buffer, Wmp in regs, MFMA ----
    short* rb = sX[(T + 1) & 1];      // buffer NOT holding final h
    const short* hb = sX[T & 1];      // final h (hi+lo)
    {
        const float2* pos2 = (const float2*)hist_pos;
        float2 pa = pos2[n0 + ag];
        float2 pb = pos2[n0 + (ag & 32)];   // scene-first agent (P=32)
        float px = pa.x - pb.x, py = pa.y - pb.y;
        int ebq = (tid & 3) << 4;
        short8 r0v, r1v;
#pragma unroll
        for (int q = 0; q < 8; ++q) {
            int e = ebq + q;
            float v = fmaf(px, sWse[e], fmaf(py, sWse[64 + e], sWse[128 + e]));
            r0v[q] = bf16rne_(fmaxf(v, 0.0f));
        }
#pragma unroll
        for (int q = 0; q < 8; ++q) {
            int e = ebq + 8 + q;
            float v = fmaf(px, sWse[e], fmaf(py, sWse[64 + e], sWse[128 + e]));
            r1v[q] = bf16rne_(fmaxf(v, 0.0f));
        }
        *(short8*)(rb + ag * XSTR + ebq)     = r0v;
        *(short8*)(rb + ag * XSTR + ebq + 8) = r1v;
    }
    // Wmp fragments: rows kt*32.. (k<64: h, k>=64: rel), col = jcol
    short8 BmH[4], BmL[4];
#pragma unroll
    for (int kt = 0; kt < 4; ++kt) {
        short8 bh, bl;
#pragma unroll
        for (int i = 0; i < 8; ++i) {
            short hh, ll; split_(Wmp[(kt * 32 + l4 * 8 + i) * 64 + jcol], hh, ll);
            bh[i] = hh; bl[i] = ll;
        }
        BmH[kt] = bh; BmL[kt] = bl;
    }
    float bmpv = bmp[jcol];
    __syncthreads();

    float smax0 = -3.4e38f, smax1 = -3.4e38f;
#pragma unroll
    for (int m = 0; m < 4; ++m) {
        const short* row  = hb + ((m << 4) + l15) * XSTR + l4 * 8;
        const short* rrow = rb + ((m << 4) + l15) * XSTR + l4 * 8;
        short8 h0 = *(const short8*)(row + 32);
        short8 h1 = *(const short8*)(row + 64);
        short8 q0 = *(const short8*)(row + 96);
        short8 q1 = *(const short8*)(row + 128);
        short8 r0 = *(const short8*)(rrow);
        short8 r1 = *(const short8*)(rrow + 32);
        f32x4 pc = (f32x4){bmpv, bmpv, bmpv, bmpv};
        pc = __builtin_amdgcn_mfma_f32_16x16x32_bf16(h0, BmH[0], pc, 0, 0, 0);
        pc = __builtin_amdgcn_mfma_f32_16x16x32_bf16(q0, BmH[0], pc, 0, 0, 0);
        pc = __builtin_amdgcn_mfma_f32_16x16x32_bf16(h0, BmL[0], pc, 0, 0, 0);
        pc = __builtin_amdgcn_mfma_f32_16x16x32_bf16(h1, BmH[1], pc, 0, 0, 0);
        pc = __builtin_amdgcn_mfma_f32_16x16x32_bf16(q1, BmH[1], pc, 0, 0, 0);
        pc = __builtin_amdgcn_mfma_f32_16x16x32_bf16(h1, BmL[1], pc, 0, 0, 0);
        pc = __builtin_amdgcn_mfma_f32_16x16x32_bf16(r0, BmH[2], pc, 0, 0, 0);
        pc = __builtin_amdgcn_mfma_f32_16x16x32_bf16(r0, BmL[2], pc, 0, 0, 0);
        pc = __builtin_amdgcn_mfma_f32_16x16x32_bf16(r1, BmH[3], pc, 0, 0, 0);
        pc = __builtin_amdgcn_mfma_f32_16x16x32_bf16(r1, BmL[3], pc, 0, 0, 0);
        float mx = fmaxf(fmaxf(pc[0], pc[1]), fmaxf(pc[2], pc[3]));
        mx = fmaxf(mx, 0.0f);   // relu(max) == max(relu)
        if (m < 2) smax0 = fmaxf(smax0, mx); else smax1 = fmaxf(smax1, mx);
    }
    smax0 = fmaxf(smax0, __shfl_xor(smax0, 16));
    smax0 = fmaxf(smax0, __shfl_xor(smax0, 32));
    smax1 = fmaxf(smax1, __shfl_xor(smax1, 16));
    smax1 = fmaxf(smax1, __shfl_xor(smax1, 32));
    if (l4 == 0) {
        int sg = blockIdx.x << 1;
        encO[sg * 128 + jcol]      = smax0;
        encO[sg * 128 + 64 + jcol] = sTgt[jcol];
    } else if (l4 == 1) {
        int sg = (blockIdx.x << 1) + 1;
        encO[sg * 128 + jcol]      = smax1;
        encO[sg * 128 + 64 + jcol] = sTgt[64 + jcol];
    }
}

// ---------------------------------------------------------------------------
// Decoder: WG = 256 threads = 4 waves = 4 scenes (unchanged, ~6% of runtime).
// ---------------------------------------------------------------------------
__global__ __launch_bounds__(256, 2) void dec_kernel(
    const float* __restrict__ enc,    // [S,128] (ws)
    const float* __restrict__ Wih_d,  // [128,256]
    const float* __restrict__ Whh_d,  // [64,256]
    const float* __restrict__ bih_d,  // [256]
    const float* __restrict__ bhh_d,  // [256]
    const float* __restrict__ Wop,    // [64,2]
    const float* __restrict__ bop,    // [2]
    float* __restrict__ out,          // [TOUT,S,2]
    int S, int TOUT)
{
    __shared__ __align__(16) float sWh[16384];   // [k64][j64][G4]
    __shared__ __align__(16) float sHd[256];     // [w4][j64]

    const int tid = threadIdx.x;
    const int j = tid & 63;
    const int w = tid >> 6;
    const int s = (blockIdx.x << 2) + w;

    for (int idx = tid; idx < 64 * 256; idx += 256) {
        int k = idx >> 8, col = idx & 255;
        sWh[((k << 6) | (col & 63)) * 4 + (col >> 6)] = Whh_d[idx];
    }
    sHd[tid] = 0.0f;

    float gx0 = bih_d[j]       + bhh_d[j];
    float gx1 = bih_d[64 + j]  + bhh_d[64 + j];
    float gx2 = bih_d[128 + j] + bhh_d[128 + j];
    float gx3 = bih_d[192 + j] + bhh_d[192 + j];
    for (int k = 0; k < 128; ++k) {
        float ev = enc[s * 128 + k];
        const float* col = Wih_d + k * 256;
        gx0 = fmaf(ev, col[j], gx0);
        gx1 = fmaf(ev, col[64 + j], gx1);
        gx2 = fmaf(ev, col[128 + j], gx2);
        gx3 = fmaf(ev, col[192 + j], gx3);
    }
    float wop0 = Wop[j * 2], wop1 = Wop[j * 2 + 1];
    float bop0 = bop[0], bop1 = bop[1];

    __syncthreads();

    const float4* Wh4 = reinterpret_cast<const float4*>(sWh);
    const float4* H4  = reinterpret_cast<const float4*>(sHd);

    float c = 0.0f;
    for (int t = 0; t < TOUT; ++t) {
        float g0 = gx0, g1 = gx1, g2 = gx2, g3 = gx3;
#pragma unroll 4
        for (int kq = 0; kq < 16; ++kq) {
            float4 hv = H4[(w << 4) + kq];
            float4 w0 = Wh4[((kq * 4 + 0) << 6) + j];
            float4 w1 = Wh4[((kq * 4 + 1) << 6) + j];
            float4 w2 = Wh4[((kq * 4 + 2) << 6) + j];
            float4 w3 = Wh4[((kq * 4 + 3) << 6) + j];
            g0 += hv.x * w0.x + hv.y * w1.x + hv.z * w2.x + hv.w * w3.x;
            g1 += hv.x * w0.y + hv.y * w1.y + hv.z * w2.y + hv.w * w3.y;
            g2 += hv.x * w0.z + hv.y * w1.z + hv.z * w2.z + hv.w * w3.z;
            g3 += hv.x * w0.w + hv.y * w1.w + hv.z * w2.w + hv.w * w3.w;
        }
        float i_ = sigmoid_(g0);
        float f_ = sigmoid_(g1);
        float gg = tanh_(g2);
        float o_ = sigmoid_(g3);
        c = fmaf(f_, c, i_ * gg);
        float h = o_ * tanh_(c);

        float r0 = h * wop0, r1 = h * wop1;
#pragma unroll
        for (int off = 32; off > 0; off >>= 1) {
            r0 += __shfl_xor(r0, off);
            r1 += __shfl_xor(r1, off);
        }
        if (j == 0) {
            float* op = out + ((size_t)t * S + s) * 2;
            op[0] = r0 + bop0;
            op[1] = r1 + bop1;
        }
        sHd[(w << 6) + j] = h;
    }
}

extern "C" void kernel_launch(void* const* d_in, const int* in_sizes, int n_in,
                              void* d_out, int out_size, void* d_ws, size_t ws_size,
                              hipStream_t stream) {
    (void)n_in; (void)ws_size;
    const float* hist     = (const float*)d_in[0];
    const float* hist_pos = (const float*)d_in[1];
    const float* W_ie     = (const float*)d_in[2];
    const float* b_ie     = (const float*)d_in[3];
    const float* Wih_e    = (const float*)d_in[4];
    const float* Whh_e    = (const float*)d_in[5];
    const float* bih_e    = (const float*)d_in[6];
    const float* bhh_e    = (const float*)d_in[7];
    const float* Wse      = (const float*)d_in[8];
    const float* bse      = (const float*)d_in[9];
    const float* Wmp      = (const float*)d_in[10];
    const float* bmp      = (const float*)d_in[11];
    const float* Wih_d    = (const float*)d_in[12];
    const float* Whh_d    = (const float*)d_in[13];
    const float* bih_d    = (const float*)d_in[14];
    const float* bhh_d    = (const float*)d_in[15];
    const float* Wop      = (const float*)d_in[16];
    const float* bop      = (const float*)d_in[17];

    const int N = in_sizes[1] / 2;
    const int T = in_sizes[0] / (N * 2);
    const int S = in_sizes[18] - 1;
    const int TOUT = out_size / (S * 2);

    float* enc = (float*)d_ws;   // [S,128] = 2 MB

    enc_pool_kernel<<<dim3(N / 64), dim3(256), 0, stream>>>(
        hist, hist_pos, W_ie, b_ie, Wih_e, Whh_e, bih_e, bhh_e,
        Wse, bse, Wmp, bmp, enc, N, T);

    dec_kernel<<<dim3(S / 4), dim3(256), 0, stream>>>(
        enc, Wih_d, Whh_d, bih_d, bhh_d, Wop, bop, (float*)d_out, S, TOUT);
}

// Round 4
// 441.141 us; speedup vs baseline: 5.9203x; 1.1062x over previous
//
#include <hip/hip_runtime.h>
#include <hip/hip_bf16.h>

// SAICNet: encoder LSTM (T=20, N=131072, E=32, H=64) via split-bf16 MFMA
// (7 terms: e*Wih + hhi*Whi + hlo*Whi + hhi*Wlo), double-buffered X,
// fused register pooling; decoder LSTM (T=30, S=4096, H=64) fp32 VALU.

typedef short short8 __attribute__((ext_vector_type(8)));
typedef float f32x4  __attribute__((ext_vector_type(4)));

__device__ __forceinline__ float rcp_(float x) { return __builtin_amdgcn_rcpf(x); }
__device__ __forceinline__ float sigmoid_(float x) { return rcp_(1.0f + __expf(-x)); }
__device__ __forceinline__ float tanh_(float x) {
    float e = __expf(-2.0f * fabsf(x));
    float t = (1.0f - e) * rcp_(1.0f + e);
    return copysignf(t, x);
}
__device__ __forceinline__ short bf16rne_(float v) {
    unsigned u = __builtin_bit_cast(unsigned, v);
    u += 0x7FFF + ((u >> 16) & 1);
    return (short)(u >> 16);
}
__device__ __forceinline__ short bf16tr_(float v) {
    return (short)(__builtin_bit_cast(unsigned, v) >> 16);
}
__device__ __forceinline__ float b2f_(short s) {
    return __builtin_bit_cast(float, ((unsigned)(unsigned short)s) << 16);
}
__device__ __forceinline__ void split_(float w, short& h, short& l) {
    h = bf16tr_(w);
    l = bf16rne_(w - b2f_(h));
}

#define XSTR 168   // shorts/row: [emb 0..31 | h_hi 32..95 | h_lo 96..159 | pad]
// 84-dword stride == 20 mod 32 -> 2-way LDS bank aliasing (free)

// ---------------------------------------------------------------------------
// Encoder + pooling. 256 threads = 4 waves; block = 64 agents (2 scenes).
// Wave p owns gate cols {64g + 16p + l15 : g=0..3} for ALL 64 agents.
// Weights in VGPRs (80 regs): Bih RNE-bf16 (no lo term - below the emb
// quantization floor), Bhh split hi/lo (drop hlo*Wlo ~2^-18).
// X double-buffered in LDS -> ONE barrier per step.
// MFMA 16x16x32 bf16: A row=l&15, k=(l>>4)*8+i; D col=l&15, row=(l>>4)*4+reg.
// ---------------------------------------------------------------------------
__global__ __launch_bounds__(256, 3) void enc_pool_kernel(
    const float* __restrict__ hist,      // [T,N,2]
    const float* __restrict__ hist_pos,  // [N,2]
    const float* __restrict__ W_ie,      // [2,32]
    const float* __restrict__ b_ie,      // [32]
    const float* __restrict__ Wih,       // [32,256]
    const float* __restrict__ Whh,       // [64,256]
    const float* __restrict__ bih,       // [256]
    const float* __restrict__ bhh,       // [256]
    const float* __restrict__ Wse,       // [2,64]
    const float* __restrict__ bse,       // [64]
    const float* __restrict__ Wmp,       // [128,64]
    const float* __restrict__ bmp,       // [64]
    float* __restrict__ encO,            // [S,128] (ws)
    int N, int T)
{
    __shared__ __align__(16) short sX[2][64 * XSTR];  // 43008 B
    __shared__ float sIE[96];    // W_ie(64)+b_ie(32)
    __shared__ float sWse[192];  // Wse(128)+bse(64)
    __shared__ float sTgt[128];  // exact h of scene-first agents [2][64]

    const int tid = threadIdx.x;
    const int l15 = tid & 15;
    const int l4  = (tid & 63) >> 4;
    const int p   = tid >> 6;           // wave id = col-tile owner
    const int n0  = blockIdx.x << 6;    // first agent of block
    const int jcol = (p << 4) + l15;    // h column this lane owns

    // ---- W fragments into registers ----
    short8 Bih[4];                  // emb k-tile, RNE bf16, per gate n
    short8 BhhH[2][4], BhhL[2][4];  // h k-tiles, split hi/lo, per gate n
    float bias[4];
#pragma unroll
    for (int n = 0; n < 4; ++n) {
        int c = (n << 6) + jcol;
        short8 bi;
#pragma unroll
        for (int i = 0; i < 8; ++i)
            bi[i] = bf16rne_(Wih[(l4 * 8 + i) * 256 + c]);
        Bih[n] = bi;
#pragma unroll
        for (int kt = 0; kt < 2; ++kt) {
            short8 ch, cl;
#pragma unroll
            for (int i = 0; i < 8; ++i) {
                short hh, ll; split_(Whh[(kt * 32 + l4 * 8 + i) * 256 + c], hh, ll);
                ch[i] = hh; cl[i] = ll;
            }
            BhhH[kt][n] = ch; BhhL[kt][n] = cl;
        }
        bias[n] = bih[c] + bhh[c];
    }

    // ---- zero buf0, stage small tables ----
    for (int i = tid; i < 64 * XSTR / 2; i += 256) ((int*)sX[0])[i] = 0;
    if (tid < 64)       sIE[tid] = W_ie[tid];
    else if (tid < 96)  sIE[tid] = b_ie[tid - 64];
    if (tid < 128)      sWse[tid] = Wse[tid];
    else if (tid < 192) sWse[tid] = bse[tid - 128];
    __syncthreads();

    const float2* hist2 = (const float2*)hist;
    const int ag = tid >> 2;          // agent this thread embeds (0..63)
    const int eb = (tid & 3) << 3;    // its 8 emb dims

    auto emb_write = [&](int t) {
        float2 xy = hist2[(size_t)t * N + n0 + ag];
        short8 ev;
#pragma unroll
        for (int q = 0; q < 8; ++q) {
            int e = eb + q;
            float v = fmaf(xy.x, sIE[e], fmaf(xy.y, sIE[32 + e], sIE[64 + e]));
            ev[q] = bf16rne_(fmaxf(v, 0.0f));
        }
        *(short8*)(sX[t & 1] + ag * XSTR + eb) = ev;
    };
    emb_write(0);
    __syncthreads();

    float cst[4][4];
#pragma unroll
    for (int m = 0; m < 4; ++m)
#pragma unroll
        for (int r = 0; r < 4; ++r) cst[m][r] = 0.0f;

    for (int t = 0; t < T; ++t) {
        const short* bR = sX[t & 1];
        short* bW = sX[(t + 1) & 1];
#pragma unroll
        for (int m = 0; m < 4; ++m) {
            const short* row = bR + ((m << 4) + l15) * XSTR + l4 * 8;
            short8 aE  = *(const short8*)(row);
            short8 aH0 = *(const short8*)(row + 32);
            short8 aH1 = *(const short8*)(row + 64);
            short8 aL0 = *(const short8*)(row + 96);
            short8 aL1 = *(const short8*)(row + 128);
            f32x4 acc[4];
#pragma unroll
            for (int n = 0; n < 4; ++n)
                acc[n] = (f32x4){bias[n], bias[n], bias[n], bias[n]};
#pragma unroll
            for (int n = 0; n < 4; ++n) {
                acc[n] = __builtin_amdgcn_mfma_f32_16x16x32_bf16(aE,  Bih[n],     acc[n], 0, 0, 0);
                acc[n] = __builtin_amdgcn_mfma_f32_16x16x32_bf16(aH0, BhhH[0][n], acc[n], 0, 0, 0);
                acc[n] = __builtin_amdgcn_mfma_f32_16x16x32_bf16(aL0, BhhH[0][n], acc[n], 0, 0, 0);
                acc[n] = __builtin_amdgcn_mfma_f32_16x16x32_bf16(aH0, BhhL[0][n], acc[n], 0, 0, 0);
                acc[n] = __builtin_amdgcn_mfma_f32_16x16x32_bf16(aH1, BhhH[1][n], acc[n], 0, 0, 0);
                acc[n] = __builtin_amdgcn_mfma_f32_16x16x32_bf16(aL1, BhhH[1][n], acc[n], 0, 0, 0);
                acc[n] = __builtin_amdgcn_mfma_f32_16x16x32_bf16(aH1, BhhL[1][n], acc[n], 0, 0, 0);
            }
#pragma unroll
            for (int r = 0; r < 4; ++r) {
                float i_ = sigmoid_(acc[0][r]);
                float f_ = sigmoid_(acc[1][r]);
                float g_ = tanh_(acc[2][r]);
                float o_ = sigmoid_(acc[3][r]);
                cst[m][r] = fmaf(f_, cst[m][r], i_ * g_);
                float h = o_ * tanh_(cst[m][r]);
                short hh = bf16tr_(h);
                short hl = bf16rne_(h - b2f_(hh));
                int rw = (m << 4) + (l4 << 2) + r;
                bW[rw * XSTR + 32 + jcol] = hh;
                bW[rw * XSTR + 96 + jcol] = hl;
                if (t == T - 1 && l4 == 0 && (m & 1) == 0 && r == 0)
                    sTgt[(m >> 1) * 64 + jcol] = h;   // exact h of scene-first agent
            }
        }
        if (t + 1 < T) emb_write(t + 1);
        __syncthreads();
    }

    // ---- social pooling: rel into dead buffer, Wmp in regs, MFMA ----
    short* rb = sX[(T + 1) & 1];      // buffer NOT holding final h
    const short* hb = sX[T & 1];      // final h (hi+lo)
    {
        const float2* pos2 = (const float2*)hist_pos;
        float2 pa = pos2[n0 + ag];
        float2 pb = pos2[n0 + (ag & 32)];   // scene-first agent (P=32)
        float px = pa.x - pb.x, py = pa.y - pb.y;
        int ebq = (tid & 3) << 4;
        short8 r0v, r1v;
#pragma unroll
        for (int q = 0; q < 8; ++q) {
            int e = ebq + q;
            float v = fmaf(px, sWse[e], fmaf(py, sWse[64 + e], sWse[128 + e]));
            r0v[q] = bf16rne_(fmaxf(v, 0.0f));
        }
#pragma unroll
        for (int q = 0; q < 8; ++q) {
            int e = ebq + 8 + q;
            float v = fmaf(px, sWse[e], fmaf(py, sWse[64 + e], sWse[128 + e]));
            r1v[q] = bf16rne_(fmaxf(v, 0.0f));
        }
        *(short8*)(rb + ag * XSTR + ebq)     = r0v;
        *(short8*)(rb + ag * XSTR + ebq + 8) = r1v;
    }
    // Wmp fragments: rows kt*32.. (k<64: h, k>=64: rel), col = jcol
    short8 BmH[4], BmL[4];
#pragma unroll
    for (int kt = 0; kt < 4; ++kt) {
        short8 bh, bl;
#pragma unroll
        for (int i = 0; i < 8; ++i) {
            short hh, ll; split_(Wmp[(kt * 32 + l4 * 8 + i) * 64 + jcol], hh, ll);
            bh[i] = hh; bl[i] = ll;
        }
        BmH[kt] = bh; BmL[kt] = bl;
    }
    float bmpv = bmp[jcol];
    __syncthreads();

    float smax0 = -3.4e38f, smax1 = -3.4e38f;
#pragma unroll
    for (int m = 0; m < 4; ++m) {
        const short* row  = hb + ((m << 4) + l15) * XSTR + l4 * 8;
        const short* rrow = rb + ((m << 4) + l15) * XSTR + l4 * 8;
        short8 h0 = *(const short8*)(row + 32);
        short8 h1 = *(const short8*)(row + 64);
        short8 q0 = *(const short8*)(row + 96);
        short8 q1 = *(const short8*)(row + 128);
        short8 r0 = *(const short8*)(rrow);
        short8 r1 = *(const short8*)(rrow + 32);
        f32x4 pc = (f32x4){bmpv, bmpv, bmpv, bmpv};
        pc = __builtin_amdgcn_mfma_f32_16x16x32_bf16(h0, BmH[0], pc, 0, 0, 0);
        pc = __builtin_amdgcn_mfma_f32_16x16x32_bf16(q0, BmH[0], pc, 0, 0, 0);
        pc = __builtin_amdgcn_mfma_f32_16x16x32_bf16(h0, BmL[0], pc, 0, 0, 0);
        pc = __builtin_amdgcn_mfma_f32_16x16x32_bf16(h1, BmH[1], pc, 0, 0, 0);
        pc = __builtin_amdgcn_mfma_f32_16x16x32_bf16(q1, BmH[1], pc, 0, 0, 0);
        pc = __builtin_amdgcn_mfma_f32_16x16x32_bf16(h1, BmL[1], pc, 0, 0, 0);
        pc = __builtin_amdgcn_mfma_f32_16x16x32_bf16(r0, BmH[2], pc, 0, 0, 0);
        pc = __builtin_amdgcn_mfma_f32_16x16x32_bf16(r0, BmL[2], pc, 0, 0, 0);
        pc = __builtin_amdgcn_mfma_f32_16x16x32_bf16(r1, BmH[3], pc, 0, 0, 0);
        pc = __builtin_amdgcn_mfma_f32_16x16x32_bf16(r1, BmL[3], pc, 0, 0, 0);
        float mx = fmaxf(fmaxf(pc[0], pc[1]), fmaxf(pc[2], pc[3]));
        mx = fmaxf(mx, 0.0f);   // relu(max) == max(relu)
        if (m < 2) smax0 = fmaxf(smax0, mx); else smax1 = fmaxf(smax1, mx);
    }
    smax0 = fmaxf(smax0, __shfl_xor(smax0, 16));
    smax0 = fmaxf(smax0, __shfl_xor(smax0, 32));
    smax1 = fmaxf(smax1, __shfl_xor(smax1, 16));
    smax1 = fmaxf(smax1, __shfl_xor(smax1, 32));
    if (l4 == 0) {
        int sg = blockIdx.x << 1;
        encO[sg * 128 + jcol]      = smax0;
        encO[sg * 128 + 64 + jcol] = sTgt[jcol];
    } else if (l4 == 1) {
        int sg = (blockIdx.x << 1) + 1;
        encO[sg * 128 + jcol]      = smax1;
        encO[sg * 128 + 64 + jcol] = sTgt[64 + jcol];
    }
}

// ---------------------------------------------------------------------------
// Decoder: WG = 256 threads = 4 waves = 4 scenes.
// ---------------------------------------------------------------------------
__global__ __launch_bounds__(256, 2) void dec_kernel(
    const float* __restrict__ enc,    // [S,128] (ws)
    const float* __restrict__ Wih_d,  // [128,256]
    const float* __restrict__ Whh_d,  // [64,256]
    const float* __restrict__ bih_d,  // [256]
    const float* __restrict__ bhh_d,  // [256]
    const float* __restrict__ Wop,    // [64,2]
    const float* __restrict__ bop,    // [2]
    float* __restrict__ out,          // [TOUT,S,2]
    int S, int TOUT)
{
    __shared__ __align__(16) float sWh[16384];   // [k64][j64][G4]
    __shared__ __align__(16) float sHd[256];     // [w4][j64]

    const int tid = threadIdx.x;
    const int j = tid & 63;
    const int w = tid >> 6;
    const int s = (blockIdx.x << 2) + w;

    for (int idx = tid; idx < 64 * 256; idx += 256) {
        int k = idx >> 8, col = idx & 255;
        sWh[((k << 6) | (col & 63)) * 4 + (col >> 6)] = Whh_d[idx];
    }
    sHd[tid] = 0.0f;

    float gx0 = bih_d[j]       + bhh_d[j];
    float gx1 = bih_d[64 + j]  + bhh_d[64 + j];
    float gx2 = bih_d[128 + j] + bhh_d[128 + j];
    float gx3 = bih_d[192 + j] + bhh_d[192 + j];
    for (int k = 0; k < 128; ++k) {
        float ev = enc[s * 128 + k];
        const float* col = Wih_d + k * 256;
        gx0 = fmaf(ev, col[j], gx0);
        gx1 = fmaf(ev, col[64 + j], gx1);
        gx2 = fmaf(ev, col[128 + j], gx2);
        gx3 = fmaf(ev, col[192 + j], gx3);
    }
    float wop0 = Wop[j * 2], wop1 = Wop[j * 2 + 1];
    float bop0 = bop[0], bop1 = bop[1];

    __syncthreads();

    const float4* Wh4 = reinterpret_cast<const float4*>(sWh);
    const float4* H4  = reinterpret_cast<const float4*>(sHd);

    float c = 0.0f;
    for (int t = 0; t < TOUT; ++t) {
        float g0 = gx0, g1 = gx1, g2 = gx2, g3 = gx3;
#pragma unroll 4
        for (int kq = 0; kq < 16; ++kq) {
            float4 hv = H4[(w << 4) + kq];
            float4 w0 = Wh4[((kq * 4 + 0) << 6) + j];
            float4 w1 = Wh4[((kq * 4 + 1) << 6) + j];
            float4 w2 = Wh4[((kq * 4 + 2) << 6) + j];
            float4 w3 = Wh4[((kq * 4 + 3) << 6) + j];
            g0 += hv.x * w0.x + hv.y * w1.x + hv.z * w2.x + hv.w * w3.x;
            g1 += hv.x * w0.y + hv.y * w1.y + hv.z * w2.y + hv.w * w3.y;
            g2 += hv.x * w0.z + hv.y * w1.z + hv.z * w2.z + hv.w * w3.z;
            g3 += hv.x * w0.w + hv.y * w1.w + hv.z * w2.w + hv.w * w3.w;
        }
        float i_ = sigmoid_(g0);
        float f_ = sigmoid_(g1);
        float gg = tanh_(g2);
        float o_ = sigmoid_(g3);
        c = fmaf(f_, c, i_ * gg);
        float h = o_ * tanh_(c);

        float r0 = h * wop0, r1 = h * wop1;
#pragma unroll
        for (int off = 32; off > 0; off >>= 1) {
            r0 += __shfl_xor(r0, off);
            r1 += __shfl_xor(r1, off);
        }
        if (j == 0) {
            float* op = out + ((size_t)t * S + s) * 2;
            op[0] = r0 + bop0;
            op[1] = r1 + bop1;
        }
        sHd[(w << 6) + j] = h;
    }
}

extern "C" void kernel_launch(void* const* d_in, const int* in_sizes, int n_in,
                              void* d_out, int out_size, void* d_ws, size_t ws_size,
                              hipStream_t stream) {
    (void)n_in; (void)ws_size;
    const float* hist     = (const float*)d_in[0];
    const float* hist_pos = (const float*)d_in[1];
    const float* W_ie     = (const float*)d_in[2];
    const float* b_ie     = (const float*)d_in[3];
    const float* Wih_e    = (const float*)d_in[4];
    const float* Whh_e    = (const float*)d_in[5];
    const float* bih_e    = (const float*)d_in[6];
    const float* bhh_e    = (const float*)d_in[7];
    const float* Wse      = (const float*)d_in[8];
    const float* bse      = (const float*)d_in[9];
    const float* Wmp      = (const float*)d_in[10];
    const float* bmp      = (const float*)d_in[11];
    const float* Wih_d    = (const float*)d_in[12];
    const float* Whh_d    = (const float*)d_in[13];
    const float* bih_d    = (const float*)d_in[14];
    const float* bhh_d    = (const float*)d_in[15];
    const float* Wop      = (const float*)d_in[16];
    const float* bop      = (const float*)d_in[17];

    const int N = in_sizes[1] / 2;
    const int T = in_sizes[0] / (N * 2);
    const int S = in_sizes[18] - 1;
    const int TOUT = out_size / (S * 2);

    float* enc = (float*)d_ws;   // [S,128] = 2 MB

    enc_pool_kernel<<<dim3(N / 64), dim3(256), 0, stream>>>(
        hist, hist_pos, W_ie, b_ie, Wih_e, Whh_e, bih_e, bhh_e,
        Wse, bse, Wmp, bmp, enc, N, T);

    dec_kernel<<<dim3(S / 4), dim3(256), 0, stream>>>(
        enc, Wih_d, Whh_d, bih_d, bhh_d, Wop, bop, (float*)d_out, S, TOUT);
}